// Round 11
// baseline (251.751 us; speedup 1.0000x reference)
//
#include <hip/hip_runtime.h>

#define B_   16
#define CIN  32
#define COUT 32
#define H_   256
#define W_   256
#define IN_ZP  3
#define OUT_ZP (-5)
#define HW (H_ * W_)
#define TH 8    // round-9 lesson: TH=16 (1024 fat blocks) REGRESSED 247.6->258.1
#define TW 64
#define SW 72   // fallback staged cols
#define SH 10   // fallback staged rows

// pre-padded packed activation buffer xp2 in d_ws (cig-INTERLEAVED layout):
//   xp2[b][ph][pw][cig], cig=0..7 innermost; word = 4 packed int8
//   (ci = 4*cig .. 4*cig+3). ph = gh+1 (gh in [-1,256]), pw = gw+4
//   (gw in [-4,259]); invalid spatial -> 0x03030303 in all 8 words.
//   One MFMA operand a[0..3] = ONE dwordx4 at word (spatial*8 + hh*4).
#define XPH 258
#define XPW 264
#define SPATIALS (B_ * XPH * XPW)     // 1,089,792 spatial positions
#define SPXCD (SPATIALS / 8)          // 136,224 spatials per XCD slice
#define XP_WORDS (SPATIALS * 8)       // 8,718,336 words = 34.87 MB
#define WS_TAB 2400                   // table words before xp2
#define WS_NEED ((size_t)(WS_TAB + XP_WORDS) * 4)
#define PACK_BLK_XCD 533              // ceil(SPXCD/256)
#define PACK_BLOCKS (8 * PACK_BLK_XCD)

// NOTE (rounds 4-10 accounting): harness re-poisons the 512 MB workspace with
// ~2 fillBufferAligned @ ~81 us = ~163 us FIXED overhead inside dur_us.
// Controllable = pack (~30 us) + fused (~50 us vs 27 floor). Six structural
// probes (DMA staging, no-staging, LDS frags, TH=16, mad24, cig-interleave)
// all landed within noise -> fused is not issue/latency/occupancy-bound.
// THIS ROUND: XCD-align pack's spatial slices with fused's consumer swizzle
// so producer and consumer share an L2 (kill cross-XCD dirty-line traffic).

using i32x4  = __attribute__((ext_vector_type(4))) int;
using i32x16 = __attribute__((ext_vector_type(16))) int;

// ws layout (ints), fast path:
//   [0 .. 2303]    weight fragments: ws[(t*64+lane)*4+g], byte b =
//                  qweight[co=lane&31][ci=16*(lane>>5)+4g+b][tap t]
//   [2304 .. 2335] sbi = sb*isc + OUT_ZP*2^fb   (sb = qbias - wsum*IN_ZP)
//   [2336 .. 2367] isc
//   [2368 .. 2399] fb
//   [2400 .. ]     xp2 (cig-interleaved packed padded activations)

// ---- kernel 1: prep (blocks 0..31) + activation pack (blocks 32..) ----
// Pack is XCD-swizzled: block bid -> XCD (bid&7) [dispatch round-robin,
// validated round 3]; 32 prep blocks = 0 mod 8 -> no phase shift. XCD k
// packs spatials [k*SPXCD, (k+1)*SPXCD) = batches {2k, 2k+1} — exactly the
// slice fused's XCD k reads. Producer/consumer L2 locality.
__global__ __launch_bounds__(256) void qconv_pack(const int* __restrict__ x,
                                                  const int* __restrict__ qw,
                                                  const int* __restrict__ qb,
                                                  const float* __restrict__ wscale,
                                                  int* __restrict__ ws) {
    const int bid = blockIdx.x;
    const int tid = threadIdx.x;
    if (bid < 32) {
        // ---- prep: weight fragments + requant tables (unchanged math) ----
        __shared__ int red[4];
        const int co = bid;
        const int* wco = qw + co * (CIN * 9);
        int s = 0;
        for (int i = tid; i < CIN * 9; i += 256) s += wco[i];
        for (int off = 32; off; off >>= 1) s += __shfl_down(s, off, 64);
        if ((tid & 63) == 0) red[tid >> 6] = s;

        if (tid < 72) {
            int gidx = co * 72 + tid;
            int g    = gidx & 3;
            int lane = (gidx >> 2) & 63;
            int t    = gidx >> 8;
            int wco2 = lane & 31;
            int ci0  = 16 * (lane >> 5) + 4 * g;
            const int* base = qw + wco2 * (CIN * 9);
            int b0 = base[(ci0 + 0) * 9 + t] & 0xff;
            int b1 = base[(ci0 + 1) * 9 + t] & 0xff;
            int b2 = base[(ci0 + 2) * 9 + t] & 0xff;
            int b3 = base[(ci0 + 3) * 9 + t] & 0xff;
            ws[gidx] = b0 | (b1 << 8) | (b2 << 16) | (b3 << 24);
        }
        __syncthreads();
        if (tid == 0) {
            int wsum = red[0] + red[1] + red[2] + red[3];
            int sb   = qb[co] - wsum * IN_ZP;
            float fs = (0.02f * wscale[co]) / 0.05f;
            float fb = floorf(log2f(127.0f / fs));
            int isc  = (int)rintf(fs * exp2f(fb));  // half-to-even = jnp.round
            int ifb  = (int)fb;
            // exact fold: ((acc+sb)*isc + zp*2^fb) >> fb == ((acc+sb)*isc)>>fb + zp
            ws[2304 + co] = sb * isc + OUT_ZP * (1 << ifb);
            ws[2336 + co] = isc;
            ws[2368 + co] = ifb;
        }
        return;
    }
    // ---- pack: thread <-> one spatial position, all 8 cig words ----
    int* __restrict__ xp = ws + WS_TAB;
    const int pb = bid - 32;
    const int k  = pb & 7;                 // XCD slice owner
    const int jb = pb >> 3;                // 0..532 within slice
    const int local = jb * 256 + tid;
    if (local >= SPXCD) return;            // ragged tail (1792 threads)
    const int q  = k * SPXCD + local;
    const int b  = q / (XPH * XPW);
    const int r  = q - b * (XPH * XPW);
    const int ph = r / XPW;
    const int pw = r - ph * XPW;
    const int gh = ph - 1, gw = pw - 4;
    const int ghc = min(H_ - 1, max(0, gh));
    const int gwc = min(W_ - 1, max(0, gw));
    const bool ok = ((unsigned)gh < (unsigned)H_) && ((unsigned)gw < (unsigned)W_);
    const int* xb = x + b * (CIN * HW) + ghc * W_ + gwc;
    i32x4 lo, hi;
#pragma unroll
    for (int cg = 0; cg < 8; ++cg) {
        int v0 = xb[(4 * cg + 0) * HW];
        int v1 = xb[(4 * cg + 1) * HW];
        int v2 = xb[(4 * cg + 2) * HW];
        int v3 = xb[(4 * cg + 3) * HW];
        int pk = (v0 & 0xff) | ((v1 & 0xff) << 8) | ((v2 & 0xff) << 16) | (v3 << 24);
        pk = ok ? pk : 0x03030303;
        if (cg < 4) lo[cg] = pk; else hi[cg - 4] = pk;
    }
    *(i32x4*)(xp + q * 8)     = lo;
    *(i32x4*)(xp + q * 8 + 4) = hi;
}

// ---- kernel 2 (fast path): cig-interleaved loads, mad24 epilogue ----
// Per tile: 9 x global_load_dwordx4 + 9 MFMA + 16 x (mad24>>fb, med3, NT st).
// Epilogue bit-exact: |acc| <= 4.68e6 < 2^23, isc <= 127; zp folds via ashr.
// __launch_bounds__(256) ONLY — no min-waves argument.
// HISTORY: (256,6)->VGPR 40 + 840MB scratch; (256,5)->VGPR 48 + 520MB scratch.
// gfx950 unified VGPR/AGPR file: a min-waves cap budgets arch VGPRs AND MFMA
// AGPRs together, starving arch allocation -> spill. Plain (256) never spilled.
// Round-7: frags in LDS -2.5us (keep VGPRs). Round-9: TH=16 regressed (keep 8).
__global__ __launch_bounds__(256) void qconv_fused(const int* __restrict__ ws,
                                                   int* __restrict__ out) {
    __shared__ __align__(16) int cons[96];  // sbi[32] | isc[32] | fb[32]

    // bijective XCD-chunked swizzle: grid = 4*32*16 = 2048 = 8 XCD * 256.
    // XCD k owns w in [256k, 256(k+1)) -> batches {2k, 2k+1}.
    const int d  = blockIdx.x + 4 * blockIdx.y + 128 * blockIdx.z;
    const int w  = ((d & 7) << 8) | (d >> 3);
    const int tx = w & 3;
    const int ty = (w >> 2) & 31;
    const int tb = w >> 7;

    const int wt = tx * TW;
    const int ht = ty * TH;
    const int tid = threadIdx.x;
    const int lane = tid & 63, wv = tid >> 6;
    const int hh  = lane >> 5;
    const int pix = lane & 31;
    const int* __restrict__ xp = ws + WS_TAB;

    if (tid < 96) cons[tid] = ws[2304 + tid];

    i32x4 wfrag[9];
    const i32x4* wsv = (const i32x4*)ws;
#pragma unroll
    for (int t = 0; t < 9; ++t) wfrag[t] = wsv[t * 64 + lane];

    __syncthreads();   // cons visible to all

    // spatial index for tile (r0,chunk), tap (dh,dw):
    //   sp = (tb*XPH + ht + r0 + dh)*XPW + wt + chunk*32 + pix + dw + 3
    // operand word addr = sp*8 + hh*4  (one dwordx4 = a[0..3])
    const int* xbase = xp + ((tb * XPH + ht) * XPW + wt + pix + 3) * 8 + hh * 4;

    // 4 M-tiles per wave; unroll 1 keeps the live set small (~80 VGPR).
#pragma unroll 1
    for (int i = 0; i < 4; ++i) {
        const int mt = wv * 4 + i;
        const int r0 = mt >> 1, chunk = mt & 1;
        const int* xt = xbase + (r0 * XPW + chunk * 32) * 8;
        i32x16 acc;
#pragma unroll
        for (int r = 0; r < 16; ++r) acc[r] = 0;
#pragma unroll
        for (int dh = 0; dh < 3; ++dh) {
#pragma unroll
            for (int dw = 0; dw < 3; ++dw) {
                i32x4 a = *(const i32x4*)(xt + (dh * XPW + dw) * 8);
                acc = __builtin_amdgcn_mfma_i32_32x32x32_i8(
                          wfrag[dh * 3 + dw], a, acc, 0, 0, 0);
            }
        }
        // epilogue: D row = co = 4*hh + 8*rg + j, D col = pix -> coalesced
        // nontemporal stores (write-once; keep L2 for xp windows)
        int* op = out + (tb * COUT) * HW + (ht + r0) * W_ + wt + chunk * 32 + pix;
#pragma unroll
        for (int rg = 0; rg < 4; ++rg) {
            const int cb = 4 * hh + 8 * rg;
            i32x4 sbi4 = *(const i32x4*)&cons[cb];
            i32x4 isc4 = *(const i32x4*)&cons[32 + cb];
            i32x4 fb4  = *(const i32x4*)&cons[64 + cb];
#pragma unroll
            for (int j = 0; j < 4; ++j) {
                int v = (__mul24(acc[rg * 4 + j], isc4[j]) + sbi4[j]) >> fb4[j];
                v = min(127, max(-128, v));   // -> v_med3_i32
                __builtin_nontemporal_store(v, op + (cb + j) * HW);
            }
        }
    }
}

// ---- fallback path (ws too small for xp2): round-3 proven kernels ----
__global__ void qconv_prep_fb(const int* __restrict__ qw, const int* __restrict__ qb,
                              const float* __restrict__ wscale, int* __restrict__ ws) {
    const int co  = blockIdx.x;
    const int tid = threadIdx.x;
    __shared__ int red[4];
    const int* wco = qw + co * (CIN * 9);
    int s = 0;
    for (int i = tid; i < CIN * 9; i += 256) s += wco[i];
    for (int off = 32; off; off >>= 1) s += __shfl_down(s, off, 64);
    if ((tid & 63) == 0) red[tid >> 6] = s;
    if (tid < 72) {
        int gidx = blockIdx.x * 72 + tid;
        int g    = gidx & 3;
        int lane = (gidx >> 2) & 63;
        int t    = gidx >> 8;
        int wco2 = lane & 31;
        int ci0  = 16 * (lane >> 5) + 4 * g;
        const int* base = qw + wco2 * (CIN * 9);
        int b0 = base[(ci0 + 0) * 9 + t] & 0xff;
        int b1 = base[(ci0 + 1) * 9 + t] & 0xff;
        int b2 = base[(ci0 + 2) * 9 + t] & 0xff;
        int b3 = base[(ci0 + 3) * 9 + t] & 0xff;
        ws[gidx] = b0 | (b1 << 8) | (b2 << 16) | (b3 << 24);
    }
    __syncthreads();
    if (tid == 0) {
        int wsum = red[0] + red[1] + red[2] + red[3];
        ws[2304 + co] = qb[co] - wsum * IN_ZP;
        float fs = (0.02f * wscale[co]) / 0.05f;
        float fb = floorf(log2f(127.0f / fs));
        int isc = (int)rintf(fs * exp2f(fb));
        ws[2336 + co] = isc | (((int)fb) << 16);
    }
}

__device__ __forceinline__ void stage_item(int idx, int ht, int wt,
                                           const int* __restrict__ xb,
                                           int (*smem)[SH][SW]) {
    int cig = idx / 180;
    int rem = idx - cig * 180;
    int r   = rem / 18;
    int c4  = rem - r * 18;
    int gh  = ht - 1 + r;
    int gw0 = wt - 4 + c4 * 4;
    int ghc = min(H_ - 1, max(0, gh));
    int gwc = min(W_ - 4, max(0, gw0));
    const int* p = xb + (cig * 4) * HW + ghc * W_ + gwc;
    i32x4 v0 = *(const i32x4*)(p);
    i32x4 v1 = *(const i32x4*)(p + HW);
    i32x4 v2 = *(const i32x4*)(p + 2 * HW);
    i32x4 v3 = *(const i32x4*)(p + 3 * HW);
    bool vh = (unsigned)gh < (unsigned)H_;
    i32x4 pk;
#pragma unroll
    for (int j = 0; j < 4; ++j) {
        int t = (v0[j] & 0xff) | ((v1[j] & 0xff) << 8) |
                ((v2[j] & 0xff) << 16) | (v3[j] << 24);
        bool ok = vh && ((unsigned)(gw0 + j) < (unsigned)W_);
        pk[j] = ok ? t : 0x03030303;
    }
    *(i32x4*)&smem[cig][r][c4 * 4] = pk;
}

__global__ __launch_bounds__(256) void qconv_fused_fb(const int* __restrict__ x,
                                                      const int* __restrict__ ws,
                                                      int* __restrict__ out) {
    __shared__ int smem[8][SH][SW];
    __shared__ __align__(16) int cons[64];
    const int d  = blockIdx.x + 4 * blockIdx.y + 128 * blockIdx.z;
    const int w  = ((d & 7) << 8) | (d >> 3);
    const int tx = w & 3;
    const int ty = (w >> 2) & 31;
    const int tb = w >> 7;
    const int wt = tx * TW;
    const int ht = ty * 8;
    const int tid = threadIdx.x;
    const int* xb = x + tb * (CIN * HW);
    if (tid < 64) cons[tid] = ws[2304 + tid];
    stage_item(tid,        ht, wt, xb, smem);
    stage_item(tid + 256,  ht, wt, xb, smem);
    stage_item(tid + 512,  ht, wt, xb, smem);
    stage_item(tid + 768,  ht, wt, xb, smem);
    stage_item(tid + 1024, ht, wt, xb, smem);
    if (tid < 160) stage_item(tid + 1280, ht, wt, xb, smem);
    __syncthreads();
    const int lane = tid & 63, wv = tid >> 6;
    const int hh  = lane >> 5;
    const int pix = lane & 31;
    i32x4 wfrag[9];
    const i32x4* wsv = (const i32x4*)ws;
#pragma unroll
    for (int t = 0; t < 9; ++t) wfrag[t] = wsv[t * 64 + lane];
#pragma unroll
    for (int i = 0; i < 4; ++i) {
        const int mt = wv * 4 + i;
        const int r0 = mt >> 1, chunk = mt & 1;
        i32x16 acc;
#pragma unroll
        for (int r = 0; r < 16; ++r) acc[r] = 0;
#pragma unroll
        for (int t = 0; t < 9; ++t) {
            const int dh = t / 3, dw = t % 3;
            const int rr = r0 + dh;
            const int c  = chunk * 32 + pix + dw + 3;
            i32x4 a;
#pragma unroll
            for (int g = 0; g < 4; ++g) a[g] = smem[4 * hh + g][rr][c];
            acc = __builtin_amdgcn_mfma_i32_32x32x32_i8(wfrag[t], a, acc, 0, 0, 0);
        }
        int* op = out + (tb * COUT) * HW + (ht + r0) * W_ + wt + chunk * 32 + pix;
#pragma unroll
        for (int rg = 0; rg < 4; ++rg) {
            const int cb = 4 * hh + 8 * rg;
            i32x4 sb4 = *(const i32x4*)&cons[cb];
            i32x4 qf4 = *(const i32x4*)&cons[32 + cb];
#pragma unroll
            for (int j = 0; j < 4; ++j) {
                int q = qf4[j];
                int v = acc[rg * 4 + j] + sb4[j];
                v = (int)((unsigned)v * (unsigned)(q & 0xffff)) >> (q >> 16);
                v += OUT_ZP;
                v = min(127, max(-128, v));
                op[(cb + j) * HW] = v;
            }
        }
    }
}

extern "C" void kernel_launch(void* const* d_in, const int* in_sizes, int n_in,
                              void* d_out, int out_size, void* d_ws, size_t ws_size,
                              hipStream_t stream) {
    const int*   x   = (const int*)d_in[0];
    const int*   qw  = (const int*)d_in[1];
    const int*   qb  = (const int*)d_in[2];
    const float* wsc = (const float*)d_in[3];
    int* ws  = (int*)d_ws;
    int* out = (int*)d_out;

    if (ws_size >= WS_NEED) {
        qconv_pack<<<32 + PACK_BLOCKS, 256, 0, stream>>>(x, qw, qb, wsc, ws);
        dim3 grid(W_ / TW, H_ / TH, B_);          // 4 x 32 x 16 = 2048
        qconv_fused<<<grid, 256, 0, stream>>>(ws, out);
    } else {
        qconv_prep_fb<<<32, 256, 0, stream>>>(qw, qb, wsc, ws);
        dim3 grid_fb(W_ / TW, H_ / 8, B_);        // 4 x 32 x 16 = 2048
        qconv_fused_fb<<<grid_fb, 256, 0, stream>>>(x, ws, out);
    }
}

// Round 12
// 248.014 us; speedup vs baseline: 1.0151x; 1.0151x over previous
//
#include <hip/hip_runtime.h>

#define B_   16
#define CIN  32
#define COUT 32
#define H_   256
#define W_   256
#define IN_ZP  3
#define OUT_ZP (-5)
#define HW (H_ * W_)
#define TH 8
#define TW 64
#define SW 72   // fallback staged cols
#define SH 10   // fallback staged rows

// pre-padded packed activation buffer xp in d_ws (plane-major layout):
//   xp[b][cig][ph][pw], word = 4 packed int8 (ci = 4*cig .. 4*cig+3)
//   ph = gh+1 (gh in [-1,256]), pw = gw+4 (gw in [-4,259]); border = 0x03030303
#define XPH 258
#define XPW 264
#define XPQ 66                        // 16B quads per row
#define PLANE_W (XPH * XPW)           // 68112 words per (b,cig) plane
#define XP_WORDS (B_ * 8 * PLANE_W)   // 8,718,336 words = 34.87 MB
#define WS_TAB 2400                   // table words before xp
#define WS_NEED ((size_t)(WS_TAB + XP_WORDS) * 4)
#define NQ (B_ * 8 * XPH * XPQ)       // 2,179,584 quads
#define PACK_BLOCKS 2176

// FINAL CONFIG (best measured: 247.6 us, round 8 of 12-round session).
// Accounting: dur_us ~= 163 us harness workspace re-poison fills (FIXED,
// 2 x 512MB fillBufferAligned @ ~81 us) + ~30 us pack (at its 170 MB HBM
// floor) + ~50 us fused. Seven structural probes on fused all landed within
// the +/-3 us noise band: global_load_lds staging (r5), staging removal (r6,
// +3), weight frags in LDS (r7, -2.5), mad24 epilogue (r8, +3), TH=16 (r9,
// -10), cig-interleaved xp / 9x dwordx4 loads (r10, -1), XCD-aligned pack
// (r11, -3). Fused is not issue-, latency-, occupancy-, or L2-locality-
// bound in any way these levers reach; remaining slack is dispatch ramps of
// two serially-dependent kernels. This source = round-8 best, verbatim.

using i32x4  = __attribute__((ext_vector_type(4))) int;
using i32x16 = __attribute__((ext_vector_type(16))) int;

// ws layout (ints), fast path:
//   [0 .. 2303]    weight fragments: ws[(t*64+lane)*4+g], byte b =
//                  qweight[co=lane&31][ci=16*(lane>>5)+4g+b][tap t]
//   [2304 .. 2335] sbi = sb*isc + OUT_ZP*2^fb   (sb = qbias - wsum*IN_ZP)
//   [2336 .. 2367] isc
//   [2368 .. 2399] fb
//   [2400 .. ]     xp (packed padded activations)

// ---- kernel 1: prep (blocks 0..31) + activation pack (blocks 32..) ----
__global__ __launch_bounds__(256) void qconv_pack(const int* __restrict__ x,
                                                  const int* __restrict__ qw,
                                                  const int* __restrict__ qb,
                                                  const float* __restrict__ wscale,
                                                  int* __restrict__ ws) {
    const int bid = blockIdx.x;
    const int tid = threadIdx.x;
    if (bid < 32) {
        // ---- prep: weight fragments + requant tables ----
        __shared__ int red[4];
        const int co = bid;
        const int* wco = qw + co * (CIN * 9);
        int s = 0;
        for (int i = tid; i < CIN * 9; i += 256) s += wco[i];
        for (int off = 32; off; off >>= 1) s += __shfl_down(s, off, 64);
        if ((tid & 63) == 0) red[tid >> 6] = s;

        if (tid < 72) {
            int gidx = co * 72 + tid;
            int g    = gidx & 3;
            int lane = (gidx >> 2) & 63;
            int t    = gidx >> 8;
            int wco2 = lane & 31;
            int ci0  = 16 * (lane >> 5) + 4 * g;
            const int* base = qw + wco2 * (CIN * 9);
            int b0 = base[(ci0 + 0) * 9 + t] & 0xff;
            int b1 = base[(ci0 + 1) * 9 + t] & 0xff;
            int b2 = base[(ci0 + 2) * 9 + t] & 0xff;
            int b3 = base[(ci0 + 3) * 9 + t] & 0xff;
            ws[gidx] = b0 | (b1 << 8) | (b2 << 16) | (b3 << 24);
        }
        __syncthreads();
        if (tid == 0) {
            int wsum = red[0] + red[1] + red[2] + red[3];
            int sb   = qb[co] - wsum * IN_ZP;
            float fs = (0.02f * wscale[co]) / 0.05f;
            float fb = floorf(log2f(127.0f / fs));
            int isc  = (int)rintf(fs * exp2f(fb));  // half-to-even = jnp.round
            int ifb  = (int)fb;
            // exact fold: ((acc+sb)*isc + zp*2^fb) >> fb == ((acc+sb)*isc)>>fb + zp
            ws[2304 + co] = sb * isc + OUT_ZP * (1 << ifb);
            ws[2336 + co] = isc;
            ws[2368 + co] = ifb;
        }
        return;
    }
    // ---- pack: streaming int32 -> padded packed int8x4 (branch-free body) ----
    int* __restrict__ xp = ws + WS_TAB;
    const int T = (PACK_BLOCKS) * 256;
    for (int q = (bid - 32) * 256 + tid; q < NQ; q += T) {
        int b   = q / (8 * XPH * XPQ);
        int r1  = q - b * (8 * XPH * XPQ);
        int cig = r1 / (XPH * XPQ);
        int r2  = r1 - cig * (XPH * XPQ);
        int ph  = r2 / XPQ;
        int cq  = r2 - ph * XPQ;
        int gh  = ph - 1;
        int gw0 = cq * 4 - 4;
        int ghc = min(H_ - 1, max(0, gh));
        int gwc = min(W_ - 4, max(0, gw0));
        const int* p = x + (b * CIN + cig * 4) * HW + ghc * W_ + gwc;
        i32x4 v0 = *(const i32x4*)(p);
        i32x4 v1 = *(const i32x4*)(p + HW);
        i32x4 v2 = *(const i32x4*)(p + 2 * HW);
        i32x4 v3 = *(const i32x4*)(p + 3 * HW);
        bool vh = (unsigned)gh < (unsigned)H_;
        i32x4 pk;
#pragma unroll
        for (int j = 0; j < 4; ++j) {
            int t = (v0[j] & 0xff) | ((v1[j] & 0xff) << 8) |
                    ((v2[j] & 0xff) << 16) | (v3[j] << 24);
            bool ok = vh && ((unsigned)(gw0 + j) < (unsigned)W_);
            pk[j] = ok ? t : 0x03030303;
        }
        *(i32x4*)(xp + 4 * q) = pk;   // dst word offset = 4q by construction
    }
}

// ---- kernel 2 (fast path): direct xp operand loads, mad24 epilogue ----
// No LDS staging (r6); wfrag in VGPRs (r7); NT stores; TH=8 / 2048 blocks (r9).
// Epilogue per output: v_mad_i32_i24(acc, isc, sbi) >> fb, med3-clamp.
// Bit-exact: |acc| <= 288*128*127 = 4.68e6 < 2^23; isc <= 127; zp folds
// through ashr exactly. __launch_bounds__(256) ONLY — no min-waves argument.
// HISTORY: (256,6)->VGPR 40 + 840MB scratch; (256,5)->VGPR 48 + 520MB scratch.
// gfx950 unified VGPR/AGPR file: a min-waves cap budgets arch VGPRs AND MFMA
// AGPRs together, starving arch allocation -> spill. Plain (256) never spilled.
__global__ __launch_bounds__(256) void qconv_fused(const int* __restrict__ ws,
                                                   int* __restrict__ out) {
    __shared__ __align__(16) int cons[96];  // sbi[32] | isc[32] | fb[32]

    // bijective XCD-chunked swizzle: grid = 4*32*16 = 2048 = 8 XCD * 256.
    const int d  = blockIdx.x + 4 * blockIdx.y + 128 * blockIdx.z;
    const int w  = ((d & 7) << 8) | (d >> 3);
    const int tx = w & 3;
    const int ty = (w >> 2) & 31;
    const int tb = w >> 7;

    const int wt = tx * TW;
    const int ht = ty * TH;
    const int tid = threadIdx.x;
    const int lane = tid & 63, wv = tid >> 6;
    const int hh  = lane >> 5;
    const int pix = lane & 31;
    const int* __restrict__ xp = ws + WS_TAB;

    if (tid < 96) cons[tid] = ws[2304 + tid];

    i32x4 wfrag[9];
    const i32x4* wsv = (const i32x4*)ws;
#pragma unroll
    for (int t = 0; t < 9; ++t) wfrag[t] = wsv[t * 64 + lane];

    __syncthreads();   // cons visible to all

    // per-lane operand base: word(cig,rr,dw) for tile (r0,chunk) =
    //   xp[(rowbase + cig*XPH + r0+dh)*XPW + wt + chunk*32 + pix + 3 + dw]
    const int rowbase = (tb * 8) * XPH + ht;
    const int* xbase = xp + rowbase * XPW + wt + pix + 3;

    // 4 M-tiles per wave; unroll 1 keeps the live set small (~80 VGPR).
#pragma unroll 1
    for (int i = 0; i < 4; ++i) {
        const int mt = wv * 4 + i;
        const int r0 = mt >> 1, chunk = mt & 1;
        const int* xt = xbase + (hh * 4) * PLANE_W + r0 * XPW + chunk * 32;
        i32x16 acc;
#pragma unroll
        for (int r = 0; r < 16; ++r) acc[r] = 0;
#pragma unroll
        for (int dh = 0; dh < 3; ++dh) {
#pragma unroll
            for (int dw = 0; dw < 3; ++dw) {
                i32x4 a;
#pragma unroll
                for (int g = 0; g < 4; ++g)
                    a[g] = xt[g * PLANE_W + dh * XPW + dw];
                acc = __builtin_amdgcn_mfma_i32_32x32x32_i8(
                          wfrag[dh * 3 + dw], a, acc, 0, 0, 0);
            }
        }
        // epilogue: D row = co = 4*hh + 8*rg + j, D col = pix -> coalesced
        // nontemporal stores (write-once; keep L2 for xp windows)
        int* op = out + (tb * COUT) * HW + (ht + r0) * W_ + wt + chunk * 32 + pix;
#pragma unroll
        for (int rg = 0; rg < 4; ++rg) {
            const int cb = 4 * hh + 8 * rg;
            i32x4 sbi4 = *(const i32x4*)&cons[cb];
            i32x4 isc4 = *(const i32x4*)&cons[32 + cb];
            i32x4 fb4  = *(const i32x4*)&cons[64 + cb];
#pragma unroll
            for (int j = 0; j < 4; ++j) {
                int v = (__mul24(acc[rg * 4 + j], isc4[j]) + sbi4[j]) >> fb4[j];
                v = min(127, max(-128, v));   // -> v_med3_i32
                __builtin_nontemporal_store(v, op + (cb + j) * HW);
            }
        }
    }
}

// ---- fallback path (ws too small for xp): round-3 proven kernels ----
__global__ void qconv_prep_fb(const int* __restrict__ qw, const int* __restrict__ qb,
                              const float* __restrict__ wscale, int* __restrict__ ws) {
    const int co  = blockIdx.x;
    const int tid = threadIdx.x;
    __shared__ int red[4];
    const int* wco = qw + co * (CIN * 9);
    int s = 0;
    for (int i = tid; i < CIN * 9; i += 256) s += wco[i];
    for (int off = 32; off; off >>= 1) s += __shfl_down(s, off, 64);
    if ((tid & 63) == 0) red[tid >> 6] = s;
    if (tid < 72) {
        int gidx = blockIdx.x * 72 + tid;
        int g    = gidx & 3;
        int lane = (gidx >> 2) & 63;
        int t    = gidx >> 8;
        int wco2 = lane & 31;
        int ci0  = 16 * (lane >> 5) + 4 * g;
        const int* base = qw + wco2 * (CIN * 9);
        int b0 = base[(ci0 + 0) * 9 + t] & 0xff;
        int b1 = base[(ci0 + 1) * 9 + t] & 0xff;
        int b2 = base[(ci0 + 2) * 9 + t] & 0xff;
        int b3 = base[(ci0 + 3) * 9 + t] & 0xff;
        ws[gidx] = b0 | (b1 << 8) | (b2 << 16) | (b3 << 24);
    }
    __syncthreads();
    if (tid == 0) {
        int wsum = red[0] + red[1] + red[2] + red[3];
        ws[2304 + co] = qb[co] - wsum * IN_ZP;
        float fs = (0.02f * wscale[co]) / 0.05f;
        float fb = floorf(log2f(127.0f / fs));
        int isc = (int)rintf(fs * exp2f(fb));
        ws[2336 + co] = isc | (((int)fb) << 16);
    }
}

__device__ __forceinline__ void stage_item(int idx, int ht, int wt,
                                           const int* __restrict__ xb,
                                           int (*smem)[SH][SW]) {
    int cig = idx / 180;
    int rem = idx - cig * 180;
    int r   = rem / 18;
    int c4  = rem - r * 18;
    int gh  = ht - 1 + r;
    int gw0 = wt - 4 + c4 * 4;
    int ghc = min(H_ - 1, max(0, gh));
    int gwc = min(W_ - 4, max(0, gw0));
    const int* p = xb + (cig * 4) * HW + ghc * W_ + gwc;
    i32x4 v0 = *(const i32x4*)(p);
    i32x4 v1 = *(const i32x4*)(p + HW);
    i32x4 v2 = *(const i32x4*)(p + 2 * HW);
    i32x4 v3 = *(const i32x4*)(p + 3 * HW);
    bool vh = (unsigned)gh < (unsigned)H_;
    i32x4 pk;
#pragma unroll
    for (int j = 0; j < 4; ++j) {
        int t = (v0[j] & 0xff) | ((v1[j] & 0xff) << 8) |
                ((v2[j] & 0xff) << 16) | (v3[j] << 24);
        bool ok = vh && ((unsigned)(gw0 + j) < (unsigned)W_);
        pk[j] = ok ? t : 0x03030303;
    }
    *(i32x4*)&smem[cig][r][c4 * 4] = pk;
}

__global__ __launch_bounds__(256) void qconv_fused_fb(const int* __restrict__ x,
                                                      const int* __restrict__ ws,
                                                      int* __restrict__ out) {
    __shared__ int smem[8][SH][SW];
    __shared__ __align__(16) int cons[64];
    const int d  = blockIdx.x + 4 * blockIdx.y + 128 * blockIdx.z;
    const int w  = ((d & 7) << 8) | (d >> 3);
    const int tx = w & 3;
    const int ty = (w >> 2) & 31;
    const int tb = w >> 7;
    const int wt = tx * TW;
    const int ht = ty * 8;
    const int tid = threadIdx.x;
    const int* xb = x + tb * (CIN * HW);
    if (tid < 64) cons[tid] = ws[2304 + tid];
    stage_item(tid,        ht, wt, xb, smem);
    stage_item(tid + 256,  ht, wt, xb, smem);
    stage_item(tid + 512,  ht, wt, xb, smem);
    stage_item(tid + 768,  ht, wt, xb, smem);
    stage_item(tid + 1024, ht, wt, xb, smem);
    if (tid < 160) stage_item(tid + 1280, ht, wt, xb, smem);
    __syncthreads();
    const int lane = tid & 63, wv = tid >> 6;
    const int hh  = lane >> 5;
    const int pix = lane & 31;
    i32x4 wfrag[9];
    const i32x4* wsv = (const i32x4*)ws;
#pragma unroll
    for (int t = 0; t < 9; ++t) wfrag[t] = wsv[t * 64 + lane];
#pragma unroll
    for (int i = 0; i < 4; ++i) {
        const int mt = wv * 4 + i;
        const int r0 = mt >> 1, chunk = mt & 1;
        i32x16 acc;
#pragma unroll
        for (int r = 0; r < 16; ++r) acc[r] = 0;
#pragma unroll
        for (int t = 0; t < 9; ++t) {
            const int dh = t / 3, dw = t % 3;
            const int rr = r0 + dh;
            const int c  = chunk * 32 + pix + dw + 3;
            i32x4 a;
#pragma unroll
            for (int g = 0; g < 4; ++g) a[g] = smem[4 * hh + g][rr][c];
            acc = __builtin_amdgcn_mfma_i32_32x32x32_i8(wfrag[t], a, acc, 0, 0, 0);
        }
        int* op = out + (tb * COUT) * HW + (ht + r0) * W_ + wt + chunk * 32 + pix;
#pragma unroll
        for (int rg = 0; rg < 4; ++rg) {
            const int cb = 4 * hh + 8 * rg;
            i32x4 sb4 = *(const i32x4*)&cons[cb];
            i32x4 qf4 = *(const i32x4*)&cons[32 + cb];
#pragma unroll
            for (int j = 0; j < 4; ++j) {
                int q = qf4[j];
                int v = acc[rg * 4 + j] + sb4[j];
                v = (int)((unsigned)v * (unsigned)(q & 0xffff)) >> (q >> 16);
                v += OUT_ZP;
                v = min(127, max(-128, v));
                op[(cb + j) * HW] = v;
            }
        }
    }
}

extern "C" void kernel_launch(void* const* d_in, const int* in_sizes, int n_in,
                              void* d_out, int out_size, void* d_ws, size_t ws_size,
                              hipStream_t stream) {
    const int*   x   = (const int*)d_in[0];
    const int*   qw  = (const int*)d_in[1];
    const int*   qb  = (const int*)d_in[2];
    const float* wsc = (const float*)d_in[3];
    int* ws  = (int*)d_ws;
    int* out = (int*)d_out;

    if (ws_size >= WS_NEED) {
        qconv_pack<<<32 + PACK_BLOCKS, 256, 0, stream>>>(x, qw, qb, wsc, ws);
        dim3 grid(W_ / TW, H_ / TH, B_);          // 4 x 32 x 16 = 2048
        qconv_fused<<<grid, 256, 0, stream>>>(ws, out);
    } else {
        qconv_prep_fb<<<32, 256, 0, stream>>>(qw, qb, wsc, ws);
        dim3 grid_fb(W_ / TW, H_ / 8, B_);        // 4 x 32 x 16 = 2048
        qconv_fused_fb<<<grid_fb, 256, 0, stream>>>(x, ws, out);
    }
}